// Round 11
// baseline (2732.465 us; speedup 1.0000x reference)
//
#include <hip/hip_runtime.h>

#define SS 8
#define BB 32
#define TT 1024
#define DD 128
#define HH 32
#define NCHAIN (SS*BB)   // 256

// d_out layout (floats): [0,4096) mixed | [4096, 4096+S*B*T*D) all_out | then hfin [S*B*H]
// all_out rows carry the hs f32 stripe at [96:128) (k_scan->k_out); k_out
// overwrites the full row. (xb stripe removed — xB is now fused into k_scan.)

// ---- numpy float32 SIMD exp: rational P5/Q2 kernel (best-scoring: R12=1.5) ----
__device__ __forceinline__ float expf_np(float x) {
  if (x > 88.72283935546875f) return __builtin_inff();
  if (x < -87.3365478515625f) return 0.0f;
  const float magic = 12582912.0f;                  // 1.5 * 2^23
  const float q = fmaf(x, 1.44269504088896341f, magic) - magic;
  float r = fmaf(q, -6.93145752e-1f, x);
  r = fmaf(q, -1.42860677e-6f, r);
  float num = fmaf(r, 5.082762527590693718096e-04f, 6.757896990527504603057e-03f);
  num = fmaf(num, r, 5.114512081637298353406e-02f);
  num = fmaf(num, r, 2.473615434895520810817e-01f);
  num = fmaf(num, r, 7.257664613233124478488e-01f);
  num = fmaf(num, r, 9.999999999980870924916e-01f);
  float den = fmaf(r, 2.159509375685829852307e-02f, -2.742335390411667452936e-01f);
  den = fmaf(den, r, 1.0f);
  return ldexpf(num / den, (int)q);
}

// ---- fast f64 exp for the softplus path: Cody-Waite + Taylor-13 (Estrin) ---
// Division-free. Numerically proven R5-R10 (passed, absmax 0.5).
__device__ __forceinline__ double exp_fast64(double x) {
  const double L2E    = 1.4426950408889634074;
  const double LN2_HI = 6.93147180369123816490e-01;
  const double LN2_LO = 1.90821492927058770002e-10;
  const double kd = rint(x * L2E);
  double t = fma(-kd, LN2_HI, x);
  t = fma(-kd, LN2_LO, t);
  const double t2 = t * t;
  const double t4 = t2 * t2;
  const double t8 = t4 * t4;
  const double qa = fma(t, 1.0 / 6.0, 0.5);                         // c2+c3 t
  const double qb = fma(t, 1.0 / 120.0, 1.0 / 24.0);                // c4+c5 t
  const double qc = fma(t, 1.0 / 5040.0, 1.0 / 720.0);              // c6+c7 t
  const double qd = fma(t, 1.0 / 362880.0, 1.0 / 40320.0);          // c8+c9 t
  const double qe = fma(t, 1.0 / 39916800.0, 1.0 / 3628800.0);      // c10+c11 t
  const double qf = fma(t, 1.0 / 6227020800.0, 1.0 / 479001600.0);  // c12+c13 t
  const double r1 = fma(t2, qb, qa);
  const double r2 = fma(t2, qd, qc);
  const double r3 = fma(t2, qf, qe);
  double q = fma(t4, r2, r1);
  q = fma(t8, r3, q);
  const double p = fma(t2, q, 1.0 + t);
  return ldexp(p, (int)kd);
}

// ---- fast f64 log1p for y in (0,1]: exact fdlibm realization, division-free.
// Proven R8-R10 (passed, absmax 0.5).
__device__ __forceinline__ double log1p_fast64(double y) {
  const double SQRT2M1 = 0.41421356237309504880168872420969808;  // sqrt(2)-1
  const double ln2_hi  = 6.93147180369123816490e-01;
  const double ln2_lo  = 1.90821492927058770002e-10;
  const double Lp1 = 6.666666666666735130e-01;
  const double Lp2 = 3.999999999940941908e-01;
  const double Lp3 = 2.857142874366239149e-01;
  const double Lp4 = 2.222219843214978396e-01;
  const double Lp5 = 1.818357216161805012e-01;
  const double Lp6 = 1.531383769920937332e-01;
  const double Lp7 = 1.479819860511658591e-01;
  const bool big = (y > SQRT2M1);
  const double kd = big ? 1.0 : 0.0;
  const double f  = big ? (y - 1.0) * 0.5 : y;   // exact in the big branch
  // s = f / (2+f), division-free: f32 rcp seed + 2 f64 Newton steps
  const double d  = 2.0 + f;
  double rr = (double)__builtin_amdgcn_rcpf((float)d);
  rr = fma(fma(-d, rr, 1.0), rr, rr);
  rr = fma(fma(-d, rr, 1.0), rr, rr);
  const double s  = f * rr;
  const double z  = s * s;
  const double z2 = z * z;
  const double z4 = z2 * z2;
  const double A1 = fma(z, Lp2, Lp1);
  const double A2 = fma(z, Lp4, Lp3);
  const double A3 = fma(z, Lp6, Lp5);
  const double B1 = fma(z2, A2, A1);
  const double B2 = fma(z2, Lp7, A3);
  const double P  = fma(z4, B2, B1);
  const double R  = z * P;
  const double hfsq = 0.5 * f * f;
  return kd * ln2_hi - ((hfsq - (s * (hfsq + R) + kd * ln2_lo)) - f);
}

// CR f32 exp/log1p via f64 (softplus scalar libm path — npy_logaddexpf).
__device__ __forceinline__ float expf_cr(float x)   { return (float)exp_fast64((double)x); }
__device__ __forceinline__ float log1pf_cr(float x) { return (float)log1p_fast64((double)x); }

// -------- 32-lane-group f32 sum reduction (k_out LN only; proven by out1) --
__device__ __forceinline__ float red32_add(float x) {
  int xi;
  xi = __builtin_amdgcn_update_dpp(0, __float_as_int(x), 0xB1, 0xF, 0xF, true);
  x += __int_as_float(xi);
  xi = __builtin_amdgcn_update_dpp(0, __float_as_int(x), 0x4E, 0xF, 0xF, true);
  x += __int_as_float(xi);
  xi = __builtin_amdgcn_update_dpp(0, __float_as_int(x), 0x141, 0xF, 0xF, true);
  x += __int_as_float(xi);
  xi = __builtin_amdgcn_update_dpp(0, __float_as_int(x), 0x140, 0xF, 0xF, true);
  x += __int_as_float(xi);
  x += __int_as_float(__builtin_amdgcn_ds_swizzle(__float_as_int(x), 0x401F));
  return x;
}

// cross-lane helpers for k_scan (single wave, 32 active lanes)
#define SWZ(x, pat) __int_as_float(__builtin_amdgcn_ds_swizzle(__float_as_int(x), (pat)))
#define DPPF(x, ctrl) __int_as_float(__builtin_amdgcn_update_dpp(0, __float_as_int(x), (ctrl), 0xF, 0xF, true))

__device__ __forceinline__ float rl_f(float v, int l) {
  return __int_as_float(__builtin_amdgcn_readlane(__float_as_int(v), l));
}

// lane^16 exchange without the DS pipe (proven R10): v_permlane16_swap_b32 +
// triple-XOR recovery — bit-exact under either operand-order semantic.
#if __has_builtin(__builtin_amdgcn_permlane16_swap)
__device__ __forceinline__ float xor16_lane(float u) {
  const unsigned ub = (unsigned)__float_as_int(u);
  auto pr = __builtin_amdgcn_permlane16_swap(ub, ub, false, false);
  return __int_as_float((int)(pr[0] ^ pr[1] ^ ub));
}
#else
__device__ __forceinline__ float xor16_lane(float u) {
  return SWZ(u, 0x401F);
}
#endif

// ================= K2: sequential scan — fused xB fold =====================
// NEW this round: k_xb is deleted; its matvec is computed inside k_scan as a
// SECOND independent dependency chain that fills the ~88% issue-idle stall
// of the serial h-recurrence. Bit-exactness of the fold: per-element
// xm = __fmul_rn(x,mask) (k_xb did plain mul), then acc=0 and d-ascending
// fmaf(xm[d], bw[d], acc) — identical operands, identical order, and the
// value now stays in-register instead of a memory round-trip (exact either
// way). Loads for row t+2 are issued at step t (one full step ≈1800cy of
// latency cover); the fold for row t+1 runs during step t; h-update at step
// t consumes xbA computed during step t-1.
// Main h-chain: byte-for-byte the R10-passing sequence.
#define SCAN_STEP(GAPC, GAPN, XLC, MLC, XLN, MLN, TCUR)                          \
  {                                                                              \
    const int tld_ = ((TCUR) + 2) & 1023;                                        \
    XLN = *(const float4*)(xg + (size_t)tld_ * DD + 4 * j);                      \
    MLN = *(const float4*)(mg + (size_t)tld_ * DD + 4 * j);                      \
    GAPN = dts[((TCUR) + 1) & 1023];                                             \
    /* xm for row TCUR+1 (numpy: x*mask elementwise-rounded) */                  \
    const float xm0_ = __fmul_rn(XLC.x, MLC.x);                                  \
    const float xm1_ = __fmul_rn(XLC.y, MLC.y);                                  \
    const float xm2_ = __fmul_rn(XLC.z, MLC.z);                                  \
    const float xm3_ = __fmul_rn(XLC.w, MLC.w);                                  \
    /* xb(TCUR+1) = sum_d xm[d]*bw[d], acc=0, d ascending (k_xb order) */        \
    float xbN_ = 0.0f;                                                           \
    _Pragma("unroll")                                                            \
    for (int l = 0; l < 32; ++l) {                                               \
      xbN_ = fmaf(rl_f(xm0_, l), bw[4 * l + 0], xbN_);                           \
      xbN_ = fmaf(rl_f(xm1_, l), bw[4 * l + 1], xbN_);                           \
      xbN_ = fmaf(rl_f(xm2_, l), bw[4 * l + 2], xbN_);                           \
      xbN_ = fmaf(rl_f(xm3_, l), bw[4 * l + 3], xbN_);                           \
    }                                                                            \
    /* ---- main h-chain (R10-proven, untouched) ---- */                         \
    float a = fmaf(w1f[0], (GAPC), 0.0f);                                        \
    _Pragma("unroll")                                                            \
    for (int k = 0; k < HH; ++k) {                                               \
      const float hk = rl_f(h_own, k);                                           \
      a = fmaf(w1f[1 + k], hk, a);                                               \
    }                                                                            \
    a = a + b1j;                                                                 \
    const float sg = 1.0f / (1.0f + expf_np(-a));                                \
    const float u = a * sg;                                                      \
    const float u16 = xor16_lane(u);         /* lane^16 — VALU permlane  */     \
    const float u8  = DPPF(u, 0x128);        /* row_ror:8 == lane^8      */     \
    const float u24 = DPPF(u16, 0x128);      /* (lane^16)^8 == lane^24   */     \
    float acc = fmaf(u,   w2a, 0.0f);                                            \
    acc = fmaf(u8,  w2b, acc);                                                   \
    acc = fmaf(u16, w2c, acc);                                                   \
    acc = fmaf(u24, w2d, acc);                                                   \
    const float acc4 = DPPF(acc, 0x104);     /* row_shl:4: lane i+4 */          \
    const float tf   = __fadd_rn(acc, acc4);                                     \
    const float p01  = __fadd_rn(tf, DPPF(tf, 0xB1));                            \
    const float rs   = __fadd_rn(p01, DPPF(p01, 0x4E));                          \
    float r = __int_as_float(__builtin_amdgcn_readfirstlane(__float_as_int(rs)));\
    r = r + b2s;                                                                 \
    const float dt0 = fmaxf(r, 0.0f) + log1pf_cr(expf_cr(-fabsf(r)));            \
    float ad = adj * dt0;                                                        \
    ad = fminf(fmaxf(ad, -20.0f), 0.0f);                                         \
    const float ab = expf_np(ad);                                                \
    {                                                                            \
      const float p1 = __fmul_rn(ab, h_own);                                     \
      const float p2 = __fmul_rn(xbA, dt0);                                      \
      float hk2 = __fadd_rn(p1, p2);                                             \
      hk2 = fminf(fmaxf(hk2, -50.0f), 50.0f);                                    \
      h_own = hk2;                                                               \
    }                                                                            \
    hsp[(size_t)(TCUR) * DD] = h_own;                                            \
    xbA = xbN_;                                                                  \
  }

__global__ __launch_bounds__(64) void k_scan(const float* __restrict__ x,
                                             const float* __restrict__ mask,
                                             const float* __restrict__ Bw,
                                             float* __restrict__ out_f,       // (float*)d_out
                                             const float* __restrict__ delta_ts,
                                             const float* __restrict__ log_neg_A,
                                             const float* __restrict__ W1,
                                             const float* __restrict__ b1,
                                             const float* __restrict__ W2,
                                             const float* __restrict__ b2,
                                             float* __restrict__ hfin) {
  const int j = threadIdx.x;    // 0..31
  const int chain = blockIdx.x;
  const int s = chain >> 5, b = chain & 31;

  float w1f[33];
  #pragma unroll
  for (int k = 0; k < 33; ++k) w1f[k] = W1[(s * HH + j) * 33 + k];
  const float b1j = b1[s * HH + j];
  const float b2s = b2[s];
  const float adj = -expf_np(log_neg_A[s * HH + j]);  // A_diag via numpy exp
  const float w2a = W2[s * HH + j];
  const float w2b = W2[s * HH + (j ^ 8)];
  const float w2c = W2[s * HH + (j ^ 16)];
  const float w2d = W2[s * HH + (j ^ 24)];

  // Bw row for this lane's output channel j: bw[d] = Bw[s][j][d]
  float bw[DD];
  {
    const float* bwp = Bw + ((size_t)s * HH + j) * DD;
    #pragma unroll
    for (int d4 = 0; d4 < DD; d4 += 4) {
      const float4 t4 = *(const float4*)(bwp + d4);
      bw[d4 + 0] = t4.x; bw[d4 + 1] = t4.y;
      bw[d4 + 2] = t4.z; bw[d4 + 3] = t4.w;
    }
  }

  const float* xg  = x    + (size_t)b * TT * DD;
  const float* mg  = mask + (size_t)b * TT * DD;
  const float* dts = delta_ts + b * TT;
  float* hsp = out_f + 4096 + (size_t)chain * TT * DD + 96 + j;

  float h_own = 0.0f;

  // prologue: xb(0) fold (exact k_xb realization), then prefetch row 1
  float xbA;
  {
    const float4 x0 = *(const float4*)(xg + 4 * j);
    const float4 m0 = *(const float4*)(mg + 4 * j);
    const float a0 = __fmul_rn(x0.x, m0.x);
    const float a1 = __fmul_rn(x0.y, m0.y);
    const float a2 = __fmul_rn(x0.z, m0.z);
    const float a3 = __fmul_rn(x0.w, m0.w);
    float acc0 = 0.0f;
    #pragma unroll
    for (int l = 0; l < 32; ++l) {
      acc0 = fmaf(rl_f(a0, l), bw[4 * l + 0], acc0);
      acc0 = fmaf(rl_f(a1, l), bw[4 * l + 1], acc0);
      acc0 = fmaf(rl_f(a2, l), bw[4 * l + 2], acc0);
      acc0 = fmaf(rl_f(a3, l), bw[4 * l + 3], acc0);
    }
    xbA = acc0;
  }
  float4 xLa = *(const float4*)(xg + DD + 4 * j);
  float4 mLa = *(const float4*)(mg + DD + 4 * j);
  float4 xLb, mLb;
  float gapA = dts[0], gapB;

  #pragma unroll 1
  for (int t = 0; t < TT; t += 2) {
    SCAN_STEP(gapA, gapB, xLa, mLa, xLb, mLb, t)
    SCAN_STEP(gapB, gapA, xLb, mLb, xLa, mLa, t + 1)
  }
  hfin[chain * HH + j] = h_own;
}

// ================= K3: y = LN(h@Cw.T + Dp*x*m)*g + b  →  all_outputs ======
__global__ __launch_bounds__(256) void k_out(float* __restrict__ out_f,
                                             const float* __restrict__ x,
                                             const float* __restrict__ mask,
                                             const float* __restrict__ Cw,
                                             const float* __restrict__ Dp,
                                             const float* __restrict__ ln_g,
                                             const float* __restrict__ ln_b) {
  __shared__ float cw_sh[HH][132];       // transposed: cw_sh[k][d]
  __shared__ float h_sh[2][8][32];
  float* all_out = out_f + 4096;
  const int tid = threadIdx.x;
  const int half = blockIdx.x & 1;
  const int chain = blockIdx.x >> 1;
  const int s = chain >> 5, b = chain & 31;
  for (int i = tid; i < DD * HH; i += 256) {
    int d = i >> 5, k = i & 31;
    cw_sh[k][d] = Cw[((size_t)s * DD + d) * HH + k];
  }
  const int grp = tid >> 5;
  const int l = tid & 31;
  const int d0 = l * 4;
  const float4 dp4 = *(const float4*)&Dp[s * DD + d0];
  const float4 g4  = *(const float4*)&ln_g[s * DD + d0];
  const float4 be4 = *(const float4*)&ln_b[s * DD + d0];
  __syncthreads();
  for (int it = 0; it < 64; ++it) {
    const int buf = it & 1;
    const int tbase = half * 512 + it * 8;
    {
      int rr = tid >> 5, k = tid & 31;
      h_sh[buf][rr][k] = all_out[((size_t)chain * TT + tbase + rr) * DD + 96 + k];
    }
    __syncthreads();
    const int t = tbase + grp;
    const size_t xoff = ((size_t)b * TT + t) * DD + d0;
    float4 xv = *(const float4*)&x[xoff];
    float4 mv = *(const float4*)&mask[xoff];
    float4 v;
    v.x = dp4.x * xv.x * mv.x;
    v.y = dp4.y * xv.y * mv.y;
    v.z = dp4.z * xv.z * mv.z;
    v.w = dp4.w * xv.w * mv.w;
    const float4* hv = (const float4*)&h_sh[buf][grp][0];
    #pragma unroll
    for (int q = 0; q < 8; ++q) {
      float4 hq = hv[q];
      float hc[4] = {hq.x, hq.y, hq.z, hq.w};
      #pragma unroll
      for (int c = 0; c < 4; ++c) {
        float4 cw = *(const float4*)&cw_sh[4 * q + c][d0];
        float hk = hc[c];
        v.x = fmaf(hk, cw.x, v.x);
        v.y = fmaf(hk, cw.y, v.y);
        v.z = fmaf(hk, cw.z, v.z);
        v.w = fmaf(hk, cw.w, v.w);
      }
    }
    float sum = red32_add((v.x + v.y) + (v.z + v.w));
    float mu = sum * (1.0f / 128.0f);
    float dx = v.x - mu, dy = v.y - mu, dz = v.z - mu, dw = v.w - mu;
    float ss = red32_add((dx * dx + dy * dy) + (dz * dz + dw * dw));
    float var = ss * (1.0f / 128.0f);
    float sc = rsqrtf(var + 1e-5f);
    float4 o;
    o.x = fmaf(dx * sc, g4.x, be4.x);
    o.y = fmaf(dy * sc, g4.y, be4.y);
    o.z = fmaf(dz * sc, g4.z, be4.z);
    o.w = fmaf(dw * sc, g4.w, be4.w);
    *(float4*)&all_out[((size_t)chain * TT + t) * DD + d0] = o;
  }
}

// ================= K4: g1[b][i] = silu(concat[b,:]·gW1[i,:] + gb1[i]) ======
__global__ __launch_bounds__(256) void k_g1(const float* __restrict__ all_out,
                                            const float* __restrict__ gW1,
                                            const float* __restrict__ gb1,
                                            float* __restrict__ g1) {
  const int idx = blockIdx.x * 256 + threadIdx.x;
  const int b = idx & 31, i = idx >> 5;
  const float* wrow = gW1 + (size_t)i * 1024;
  float a0 = 0.f, a1 = 0.f, a2 = 0.f, a3 = 0.f;
  for (int j4 = 0; j4 < 1024; j4 += 4) {
    float4 w = *(const float4*)&wrow[j4];
    int sI = j4 >> 7, d = j4 & 127;
    float4 c = *(const float4*)&all_out[(((size_t)(sI * 32 + b)) * TT + 1023) * DD + d];
    a0 = fmaf(w.x, c.x, a0);
    a1 = fmaf(w.y, c.y, a1);
    a2 = fmaf(w.z, c.z, a2);
    a3 = fmaf(w.w, c.w, a3);
  }
  float r = (a0 + a1) + (a2 + a3) + gb1[i];
  g1[b * 1024 + i] = r * (1.0f / (1.0f + expf(-r)));
}

// ================= K5: gates + mixed ======================================
__global__ __launch_bounds__(256) void k_gate(const float* __restrict__ g1,
                                              const float* __restrict__ gW2,
                                              const float* __restrict__ gb2,
                                              const float* __restrict__ all_out,
                                              float* __restrict__ mixed) {
  __shared__ float gates_sh[32][8];
  const int tid = threadIdx.x;
  const int b = tid & 31, s2 = tid >> 5;
  const float* grow = g1 + b * 1024;
  const float* wrow = gW2 + s2 * 1024;
  float a0 = 0.f, a1 = 0.f, a2 = 0.f, a3 = 0.f;
  for (int i = 0; i < 1024; i += 4) {
    float4 gg = *(const float4*)&grow[i];
    float4 w  = *(const float4*)&wrow[i];
    a0 = fmaf(gg.x, w.x, a0);
    a1 = fmaf(gg.y, w.y, a1);
    a2 = fmaf(gg.z, w.z, a2);
    a3 = fmaf(gg.w, w.w, a3);
  }
  float r = (a0 + a1) + (a2 + a3) + gb2[s2];
  gates_sh[b][s2] = 1.0f / (1.0f + expf(-r));
  __syncthreads();
  for (int m = tid; m < BB * DD; m += 256) {
    int bb = m >> 7, d = m & 127;
    float acc = 0.f;
    #pragma unroll
    for (int ss2 = 0; ss2 < 8; ++ss2)
      acc = fmaf(all_out[(((size_t)(ss2 * 32 + bb)) * TT + 1023) * DD + d],
                 gates_sh[bb][ss2], acc);
    mixed[m] = acc;
  }
}

// ===========================================================================
extern "C" void kernel_launch(void* const* d_in, const int* in_sizes, int n_in,
                              void* d_out, int out_size, void* d_ws, size_t ws_size,
                              hipStream_t stream) {
  const float* x         = (const float*)d_in[0];
  const float* delta_ts  = (const float*)d_in[1];
  const float* mask      = (const float*)d_in[2];
  const float* log_neg_A = (const float*)d_in[3];
  const float* Bw        = (const float*)d_in[4];
  const float* Cw        = (const float*)d_in[5];
  const float* Dp        = (const float*)d_in[6];
  const float* W1        = (const float*)d_in[7];
  const float* b1        = (const float*)d_in[8];
  const float* W2        = (const float*)d_in[9];
  const float* b2        = (const float*)d_in[10];
  const float* ln_g      = (const float*)d_in[11];
  const float* ln_b      = (const float*)d_in[12];
  const float* gW1       = (const float*)d_in[13];
  const float* gb1       = (const float*)d_in[14];
  const float* gW2       = (const float*)d_in[15];
  const float* gb2       = (const float*)d_in[16];

  float*  out_f   = (float*)d_out;
  float*  mixed   = out_f;                                    // [32,128]
  float*  all_out = out_f + 4096;                             // [8,32,1024,128]
  float*  hfin    = out_f + 4096 + (size_t)SS * BB * TT * DD; // [8,32,32]

  float* g1 = (float*)d_ws;                                   // [32][1024]

  k_scan<<<NCHAIN, 32, 0, stream>>>(x, mask, Bw, out_f, delta_ts, log_neg_A, W1, b1, W2, b2, hfin);
  k_out <<<NCHAIN * 2, 256, 0, stream>>>(out_f, x, mask, Cw, Dp, ln_g, ln_b);
  k_g1  <<<BB * 1024 / 256, 256, 0, stream>>>(all_out, gW1, gb1, g1);
  k_gate<<<1, 256, 0, stream>>>(g1, gW2, gb2, all_out, mixed);
}

// Round 13
// 1040.440 us; speedup vs baseline: 2.6263x; 2.6263x over previous
//
#include <hip/hip_runtime.h>

#define SS 8
#define BB 32
#define TT 1024
#define DD 128
#define HH 32
#define NCHAIN (SS*BB)   // 256

// d_out layout (floats): [0,4096) mixed | [4096, 4096+S*B*T*D) all_out | then hfin [S*B*H]
// Stripes per all_out row (128 floats): [0:32) xB f32 (k_xb->k_scan), [96:128) hs f32
// (k_scan->k_out). k_out reads the hs stripe then overwrites the full row.

// ---- numpy float32 SIMD exp: rational P5/Q2 kernel (best-scoring: R12=1.5) ----
__device__ __forceinline__ float expf_np(float x) {
  if (x > 88.72283935546875f) return __builtin_inff();
  if (x < -87.3365478515625f) return 0.0f;
  const float magic = 12582912.0f;                  // 1.5 * 2^23
  const float q = fmaf(x, 1.44269504088896341f, magic) - magic;
  float r = fmaf(q, -6.93145752e-1f, x);
  r = fmaf(q, -1.42860677e-6f, r);
  float num = fmaf(r, 5.082762527590693718096e-04f, 6.757896990527504603057e-03f);
  num = fmaf(num, r, 5.114512081637298353406e-02f);
  num = fmaf(num, r, 2.473615434895520810817e-01f);
  num = fmaf(num, r, 7.257664613233124478488e-01f);
  num = fmaf(num, r, 9.999999999980870924916e-01f);
  float den = fmaf(r, 2.159509375685829852307e-02f, -2.742335390411667452936e-01f);
  den = fmaf(den, r, 1.0f);
  return ldexpf(num / den, (int)q);
}

// ---- fast f64 exp for the softplus path: Cody-Waite + Taylor-13 (Estrin) ---
// Division-free. Numerically proven R5-R11 (passed, absmax 0.5).
__device__ __forceinline__ double exp_fast64(double x) {
  const double L2E    = 1.4426950408889634074;
  const double LN2_HI = 6.93147180369123816490e-01;
  const double LN2_LO = 1.90821492927058770002e-10;
  const double kd = rint(x * L2E);
  double t = fma(-kd, LN2_HI, x);
  t = fma(-kd, LN2_LO, t);
  const double t2 = t * t;
  const double t4 = t2 * t2;
  const double t8 = t4 * t4;
  const double qa = fma(t, 1.0 / 6.0, 0.5);                         // c2+c3 t
  const double qb = fma(t, 1.0 / 120.0, 1.0 / 24.0);                // c4+c5 t
  const double qc = fma(t, 1.0 / 5040.0, 1.0 / 720.0);              // c6+c7 t
  const double qd = fma(t, 1.0 / 362880.0, 1.0 / 40320.0);          // c8+c9 t
  const double qe = fma(t, 1.0 / 39916800.0, 1.0 / 3628800.0);      // c10+c11 t
  const double qf = fma(t, 1.0 / 6227020800.0, 1.0 / 479001600.0);  // c12+c13 t
  const double r1 = fma(t2, qb, qa);
  const double r2 = fma(t2, qd, qc);
  const double r3 = fma(t2, qf, qe);
  double q = fma(t4, r2, r1);
  q = fma(t8, r3, q);
  const double p = fma(t2, q, 1.0 + t);
  return ldexp(p, (int)kd);
}

// ---- fast f64 log1p for y in (0,1]: exact fdlibm realization, division-free.
// Proven R8-R11 (passed, absmax 0.5).
__device__ __forceinline__ double log1p_fast64(double y) {
  const double SQRT2M1 = 0.41421356237309504880168872420969808;  // sqrt(2)-1
  const double ln2_hi  = 6.93147180369123816490e-01;
  const double ln2_lo  = 1.90821492927058770002e-10;
  const double Lp1 = 6.666666666666735130e-01;
  const double Lp2 = 3.999999999940941908e-01;
  const double Lp3 = 2.857142874366239149e-01;
  const double Lp4 = 2.222219843214978396e-01;
  const double Lp5 = 1.818357216161805012e-01;
  const double Lp6 = 1.531383769920937332e-01;
  const double Lp7 = 1.479819860511658591e-01;
  const bool big = (y > SQRT2M1);
  const double kd = big ? 1.0 : 0.0;
  const double f  = big ? (y - 1.0) * 0.5 : y;   // exact in the big branch
  // s = f / (2+f), division-free: f32 rcp seed + 2 f64 Newton steps
  const double d  = 2.0 + f;
  double rr = (double)__builtin_amdgcn_rcpf((float)d);
  rr = fma(fma(-d, rr, 1.0), rr, rr);
  rr = fma(fma(-d, rr, 1.0), rr, rr);
  const double s  = f * rr;
  const double z  = s * s;
  const double z2 = z * z;
  const double z4 = z2 * z2;
  const double A1 = fma(z, Lp2, Lp1);
  const double A2 = fma(z, Lp4, Lp3);
  const double A3 = fma(z, Lp6, Lp5);
  const double B1 = fma(z2, A2, A1);
  const double B2 = fma(z2, Lp7, A3);
  const double P  = fma(z4, B2, B1);
  const double R  = z * P;
  const double hfsq = 0.5 * f * f;
  return kd * ln2_hi - ((hfsq - (s * (hfsq + R) + kd * ln2_lo)) - f);
}

// CR f32 exp/log1p via f64 (softplus scalar libm path — npy_logaddexpf).
__device__ __forceinline__ float expf_cr(float x)   { return (float)exp_fast64((double)x); }
__device__ __forceinline__ float log1pf_cr(float x) { return (float)log1p_fast64((double)x); }

// -------- 32-lane-group f32 sum reduction (k_out LN only; proven by out1) --
__device__ __forceinline__ float red32_add(float x) {
  int xi;
  xi = __builtin_amdgcn_update_dpp(0, __float_as_int(x), 0xB1, 0xF, 0xF, true);
  x += __int_as_float(xi);
  xi = __builtin_amdgcn_update_dpp(0, __float_as_int(x), 0x4E, 0xF, 0xF, true);
  x += __int_as_float(xi);
  xi = __builtin_amdgcn_update_dpp(0, __float_as_int(x), 0x141, 0xF, 0xF, true);
  x += __int_as_float(xi);
  xi = __builtin_amdgcn_update_dpp(0, __float_as_int(x), 0x140, 0xF, 0xF, true);
  x += __int_as_float(xi);
  x += __int_as_float(__builtin_amdgcn_ds_swizzle(__float_as_int(x), 0x401F));
  return x;
}

// cross-lane helpers (k_scan: single wave, 32 active lanes)
#define SWZ(x, pat) __int_as_float(__builtin_amdgcn_ds_swizzle(__float_as_int(x), (pat)))
#define DPPF(x, ctrl) __int_as_float(__builtin_amdgcn_update_dpp(0, __float_as_int(x), (ctrl), 0xF, 0xF, true))

__device__ __forceinline__ float rl_f(float v, int l) {
  return __int_as_float(__builtin_amdgcn_readlane(__float_as_int(v), l));
}

// lane^16 exchange without the DS pipe (proven R10): v_permlane16_swap_b32 +
// triple-XOR recovery — bit-exact under either operand-order semantic.
#if __has_builtin(__builtin_amdgcn_permlane16_swap)
__device__ __forceinline__ float xor16_lane(float u) {
  const unsigned ub = (unsigned)__float_as_int(u);
  auto pr = __builtin_amdgcn_permlane16_swap(ub, ub, false, false);
  return __int_as_float((int)(pr[0] ^ pr[1] ^ ub));
}
#else
__device__ __forceinline__ float xor16_lane(float u) {
  return SWZ(u, 0x401F);
}
#endif

// ================= K1: xB f32 stripes — k-sequential FMA (sgemm order) =====
__global__ __launch_bounds__(256) void k_xb(const float* __restrict__ x,
                                            const float* __restrict__ mask,
                                            const float* __restrict__ Bw,
                                            float* __restrict__ xb) { // = (float*)d_out + 4096
  __shared__ float bw_sh[HH][132];
  __shared__ float x_sh[8][132];
  const int r0 = blockIdx.x * 8;           // 8 rows, all within one chain
  const int chain = r0 >> 10;
  const int s = chain >> 5;
  const int b = chain & 31;
  const int tid = threadIdx.x;
  for (int i = tid; i < HH * DD; i += 256)
    bw_sh[i >> 7][i & 127] = Bw[s * HH * DD + i];
  const int t0 = r0 & 1023;
  for (int i = tid; i < 8 * DD; i += 256) {
    int rr = i >> 7, d = i & 127;
    size_t gidx = ((size_t)b * TT + t0 + rr) * DD + d;
    x_sh[rr][d] = x[gidx] * mask[gidx];
  }
  __syncthreads();
  const int rl = tid >> 5;
  const int j  = tid & 31;
  float a = 0.0f;                          // acc=0; k ascending; FMA each term
  for (int d = 0; d < DD; ++d)
    a = fmaf(x_sh[rl][d], bw_sh[j][d], a);
  xb[(size_t)(r0 + rl) * DD + j] = a;      // stripe: floats [0:32) of the row
}

// ================= K2: sequential scan — R10-proven (797 µs) ==============
#define SCAN_STEP(GAPC, XOWNC, GAPN, XOWNN, TCUR, TNXT)                          \
  {                                                                              \
    GAPN  = dts[(TNXT)];                                                         \
    XOWNN = xrow[(size_t)(TNXT) * DD + j];                                       \
    float a = fmaf(w1f[0], (GAPC), 0.0f);                                        \
    _Pragma("unroll")                                                            \
    for (int k = 0; k < HH; ++k) {                                               \
      const float hk = rl_f(h_own, k);                                           \
      a = fmaf(w1f[1 + k], hk, a);                                               \
    }                                                                            \
    a = a + b1j;                                                                 \
    const float sg = 1.0f / (1.0f + expf_np(-a));                                \
    const float u = a * sg;                                                      \
    const float u16 = xor16_lane(u);         /* lane^16 — VALU permlane  */     \
    const float u8  = DPPF(u, 0x128);        /* row_ror:8 == lane^8      */     \
    const float u24 = DPPF(u16, 0x128);      /* (lane^16)^8 == lane^24   */     \
    float acc = fmaf(u,   w2a, 0.0f);                                            \
    acc = fmaf(u8,  w2b, acc);                                                   \
    acc = fmaf(u16, w2c, acc);                                                   \
    acc = fmaf(u24, w2d, acc);                                                   \
    const float acc4 = DPPF(acc, 0x104);     /* row_shl:4: lane i+4 */          \
    const float tf   = __fadd_rn(acc, acc4);                                     \
    const float p01  = __fadd_rn(tf, DPPF(tf, 0xB1));                            \
    const float rs   = __fadd_rn(p01, DPPF(p01, 0x4E));                          \
    float r = __int_as_float(__builtin_amdgcn_readfirstlane(__float_as_int(rs)));\
    r = r + b2s;                                                                 \
    const float dt0 = fmaxf(r, 0.0f) + log1pf_cr(expf_cr(-fabsf(r)));            \
    float ad = adj * dt0;                                                        \
    ad = fminf(fmaxf(ad, -20.0f), 0.0f);                                         \
    const float ab = expf_np(ad);                                                \
    {                                                                            \
      const float p1 = __fmul_rn(ab, h_own);                                     \
      const float p2 = __fmul_rn((XOWNC), dt0);                                  \
      float hk2 = __fadd_rn(p1, p2);                                             \
      hk2 = fminf(fmaxf(hk2, -50.0f), 50.0f);                                    \
      h_own = hk2;                                                               \
    }                                                                            \
    hsp[(size_t)(TCUR) * DD] = h_own;                                            \
  }

__global__ __launch_bounds__(64) void k_scan(const float* __restrict__ xb,    // (float*)d_out + 4096
                                             float* __restrict__ out_f,       // (float*)d_out
                                             const float* __restrict__ delta_ts,
                                             const float* __restrict__ log_neg_A,
                                             const float* __restrict__ W1,
                                             const float* __restrict__ b1,
                                             const float* __restrict__ W2,
                                             const float* __restrict__ b2,
                                             float* __restrict__ hfin) {
  const int j = threadIdx.x;    // 0..31
  const int chain = blockIdx.x;
  const int s = chain >> 5, b = chain & 31;

  float w1f[33];
  #pragma unroll
  for (int k = 0; k < 33; ++k) w1f[k] = W1[(s * HH + j) * 33 + k];
  const float b1j = b1[s * HH + j];
  const float b2s = b2[s];
  const float adj = -expf_np(log_neg_A[s * HH + j]);  // A_diag via numpy exp
  const float w2a = W2[s * HH + j];
  const float w2b = W2[s * HH + (j ^ 8)];
  const float w2c = W2[s * HH + (j ^ 16)];
  const float w2d = W2[s * HH + (j ^ 24)];

  const float* xrow = xb + (size_t)chain * TT * DD;     // row t: xrow + t*DD, [0:32)
  const float* dts  = delta_ts + b * TT;
  float* hsp = out_f + 4096 + (size_t)chain * TT * DD + 96 + j;

  float h_own = 0.0f;

  // prologue prefetch t=0 into the A registers
  float gapA  = dts[0], gapB;
  float xownA = xrow[j], xownB;

  #pragma unroll 1
  for (int t = 0; t < TT; t += 2) {
    SCAN_STEP(gapA, xownA, gapB, xownB, t, t + 1)
    SCAN_STEP(gapB, xownB, gapA, xownA, t + 1, (t + 2) & 1023)
  }
  hfin[chain * HH + j] = h_own;
}

// ================= K3: y = LN(h@Cw.T + Dp*x*m)*g + b  →  all_outputs ======
// R13 fix of the R12 wave-width bug: broadcast goes back through LDS (R10's
// exact data path — h_sh staged per warp, read back as float4s, identical
// bits), but the per-iteration __syncthreads are REMOVED: warp grp writes
// h_sh[grp][l] and reads only h_sh[grp][*] — all sharing is intra-wave, and
// same-wave DS ops execute in program order (write/read may-alias, so the
// compiler preserves ordering and inserts the lgkmcnt). readlane is NOT used
// here (256-thread block = 4 waves of 64; v_readlane indexes the 64-lane
// wave — that was R12's wrong-row bug). Only the cw_sh init barrier
// (genuinely cross-wave) remains.
__global__ __launch_bounds__(256) void k_out(float* __restrict__ out_f,
                                             const float* __restrict__ x,
                                             const float* __restrict__ mask,
                                             const float* __restrict__ Cw,
                                             const float* __restrict__ Dp,
                                             const float* __restrict__ ln_g,
                                             const float* __restrict__ ln_b) {
  __shared__ float cw_sh[HH][132];       // transposed: cw_sh[k][d]
  __shared__ float h_sh[8][32];          // one row-stripe per warp (warp-local)
  float* all_out = out_f + 4096;
  const int tid = threadIdx.x;
  const int half = blockIdx.x & 1;
  const int chain = blockIdx.x >> 1;
  const int s = chain >> 5, b = chain & 31;
  for (int i = tid; i < DD * HH; i += 256) {
    int d = i >> 5, k = i & 31;
    cw_sh[k][d] = Cw[((size_t)s * DD + d) * HH + k];
  }
  const int grp = tid >> 5;
  const int l = tid & 31;
  const int d0 = l * 4;
  const float4 dp4 = *(const float4*)&Dp[s * DD + d0];
  const float4 g4  = *(const float4*)&ln_g[s * DD + d0];
  const float4 be4 = *(const float4*)&ln_b[s * DD + d0];
  __syncthreads();                       // cw_sh is cross-wave — keep this one
  for (int it = 0; it < 64; ++it) {
    const int t = half * 512 + it * 8 + grp;
    // stage own row's hs stripe through LDS (warp-local; no barrier needed)
    h_sh[grp][l] = all_out[((size_t)chain * TT + t) * DD + 96 + l];
    const size_t xoff = ((size_t)b * TT + t) * DD + d0;
    float4 xv = *(const float4*)&x[xoff];
    float4 mv = *(const float4*)&mask[xoff];
    float4 v;
    v.x = dp4.x * xv.x * mv.x;
    v.y = dp4.y * xv.y * mv.y;
    v.z = dp4.z * xv.z * mv.z;
    v.w = dp4.w * xv.w * mv.w;
    const float4* hv = (const float4*)&h_sh[grp][0];
    #pragma unroll
    for (int q = 0; q < 8; ++q) {
      float4 hq = hv[q];
      float hc[4] = {hq.x, hq.y, hq.z, hq.w};
      #pragma unroll
      for (int c = 0; c < 4; ++c) {
        float4 cw = *(const float4*)&cw_sh[4 * q + c][d0];
        float hk = hc[c];
        v.x = fmaf(hk, cw.x, v.x);
        v.y = fmaf(hk, cw.y, v.y);
        v.z = fmaf(hk, cw.z, v.z);
        v.w = fmaf(hk, cw.w, v.w);
      }
    }
    float sum = red32_add((v.x + v.y) + (v.z + v.w));
    float mu = sum * (1.0f / 128.0f);
    float dx = v.x - mu, dy = v.y - mu, dz = v.z - mu, dw = v.w - mu;
    float ss = red32_add((dx * dx + dy * dy) + (dz * dz + dw * dw));
    float var = ss * (1.0f / 128.0f);
    float sc = rsqrtf(var + 1e-5f);
    float4 o;
    o.x = fmaf(dx * sc, g4.x, be4.x);
    o.y = fmaf(dy * sc, g4.y, be4.y);
    o.z = fmaf(dz * sc, g4.z, be4.z);
    o.w = fmaf(dw * sc, g4.w, be4.w);
    *(float4*)&all_out[((size_t)chain * TT + t) * DD + d0] = o;
  }
}

// ================= K4: g1[b][i] = silu(concat[b,:]·gW1[i,:] + gb1[i]) ======
__global__ __launch_bounds__(256) void k_g1(const float* __restrict__ all_out,
                                            const float* __restrict__ gW1,
                                            const float* __restrict__ gb1,
                                            float* __restrict__ g1) {
  const int idx = blockIdx.x * 256 + threadIdx.x;
  const int b = idx & 31, i = idx >> 5;
  const float* wrow = gW1 + (size_t)i * 1024;
  float a0 = 0.f, a1 = 0.f, a2 = 0.f, a3 = 0.f;
  for (int j4 = 0; j4 < 1024; j4 += 4) {
    float4 w = *(const float4*)&wrow[j4];
    int sI = j4 >> 7, d = j4 & 127;
    float4 c = *(const float4*)&all_out[(((size_t)(sI * 32 + b)) * TT + 1023) * DD + d];
    a0 = fmaf(w.x, c.x, a0);
    a1 = fmaf(w.y, c.y, a1);
    a2 = fmaf(w.z, c.z, a2);
    a3 = fmaf(w.w, c.w, a3);
  }
  float r = (a0 + a1) + (a2 + a3) + gb1[i];
  g1[b * 1024 + i] = r * (1.0f / (1.0f + expf(-r)));
}

// ================= K5: gates + mixed ======================================
__global__ __launch_bounds__(256) void k_gate(const float* __restrict__ g1,
                                              const float* __restrict__ gW2,
                                              const float* __restrict__ gb2,
                                              const float* __restrict__ all_out,
                                              float* __restrict__ mixed) {
  __shared__ float gates_sh[32][8];
  const int tid = threadIdx.x;
  const int b = tid & 31, s2 = tid >> 5;
  const float* grow = g1 + b * 1024;
  const float* wrow = gW2 + s2 * 1024;
  float a0 = 0.f, a1 = 0.f, a2 = 0.f, a3 = 0.f;
  for (int i = 0; i < 1024; i += 4) {
    float4 gg = *(const float4*)&grow[i];
    float4 w  = *(const float4*)&wrow[i];
    a0 = fmaf(gg.x, w.x, a0);
    a1 = fmaf(gg.y, w.y, a1);
    a2 = fmaf(gg.z, w.z, a2);
    a3 = fmaf(gg.w, w.w, a3);
  }
  float r = (a0 + a1) + (a2 + a3) + gb2[s2];
  gates_sh[b][s2] = 1.0f / (1.0f + expf(-r));
  __syncthreads();
  for (int m = tid; m < BB * DD; m += 256) {
    int bb = m >> 7, d = m & 127;
    float acc = 0.f;
    #pragma unroll
    for (int ss2 = 0; ss2 < 8; ++ss2)
      acc = fmaf(all_out[(((size_t)(ss2 * 32 + bb)) * TT + 1023) * DD + d],
                 gates_sh[bb][ss2], acc);
    mixed[m] = acc;
  }
}

// ===========================================================================
extern "C" void kernel_launch(void* const* d_in, const int* in_sizes, int n_in,
                              void* d_out, int out_size, void* d_ws, size_t ws_size,
                              hipStream_t stream) {
  const float* x         = (const float*)d_in[0];
  const float* delta_ts  = (const float*)d_in[1];
  const float* mask      = (const float*)d_in[2];
  const float* log_neg_A = (const float*)d_in[3];
  const float* Bw        = (const float*)d_in[4];
  const float* Cw        = (const float*)d_in[5];
  const float* Dp        = (const float*)d_in[6];
  const float* W1        = (const float*)d_in[7];
  const float* b1        = (const float*)d_in[8];
  const float* W2        = (const float*)d_in[9];
  const float* b2        = (const float*)d_in[10];
  const float* ln_g      = (const float*)d_in[11];
  const float* ln_b      = (const float*)d_in[12];
  const float* gW1       = (const float*)d_in[13];
  const float* gb1       = (const float*)d_in[14];
  const float* gW2       = (const float*)d_in[15];
  const float* gb2       = (const float*)d_in[16];

  float*  out_f   = (float*)d_out;
  float*  mixed   = out_f;                                    // [32,128]
  float*  all_out = out_f + 4096;                             // [8,32,1024,128]
  float*  hfin    = out_f + 4096 + (size_t)SS * BB * TT * DD; // [8,32,32]
  float*  xb      = out_f + 4096;                             // xB stripes inside all_out

  float* g1 = (float*)d_ws;                                   // [32][1024]

  k_xb  <<<NCHAIN * TT / 8, 256, 0, stream>>>(x, mask, Bw, xb);
  k_scan<<<NCHAIN, 32, 0, stream>>>(xb, out_f, delta_ts, log_neg_A, W1, b1, W2, b2, hfin);
  k_out <<<NCHAIN * 2, 256, 0, stream>>>(out_f, x, mask, Cw, Dp, ln_g, ln_b);
  k_g1  <<<BB * 1024 / 256, 256, 0, stream>>>(all_out, gW1, gb1, g1);
  k_gate<<<1, 256, 0, stream>>>(g1, gW2, gb2, all_out, mixed);
}